// Round 17
// baseline (271.912 us; speedup 1.0000x reference)
//
#include <hip/hip_runtime.h>
#include <hip/hip_bf16.h>
#include <math.h>

// Problem constants
#define BB 16
#define NN 3136
#define CC 384
#define HDS 8
#define DHH 48
#define AGG 49
#define HI 56
#define WI 56
#define OUTD 1000
#define SCALE_F 0.14433756729740643f  // 48^-0.5
#define QKVC 1152                     // q|k|v column stride

typedef __attribute__((ext_vector_type(8))) short short8;
typedef __attribute__((ext_vector_type(4))) float f32x4;

__device__ __forceinline__ float bf2f(unsigned short u) {
  union { unsigned u32; float f; } x;
  x.u32 = ((unsigned)u) << 16;
  return x.f;
}
__device__ __forceinline__ unsigned short f2bf(float f) {
  union { float f; unsigned u; } x;
  x.f = f;
  unsigned u = x.u;
  unsigned r = (u + 0x7fffu + ((u >> 16) & 1u)) >> 16;
  return (unsigned short)r;
}

// Fragment-pack offset functions (shared by producer & consumer).
__device__ __forceinline__ size_t xp_off(int gb, int ks, int j, int lane) {
  return ((((size_t)gb * 12 + ks) * 4 + j) * 64 + lane) * 8;
}
__device__ __forceinline__ size_t wp_off(int blk, int ks, int i, int lane) {
  return ((((size_t)blk * 12 + ks) * 4 + i) * 64 + lane) * 8;
}
// vtp: V^T fragments: [bh][chunk49][half2][ntd3][lane64][8]
__device__ __forceinline__ size_t vtp_off(int bh, int chunk, int half, int ntd, int lane) {
  return ((((size_t)bh * 49 + chunk) * 2 + half) * 3 + ntd) * 512 + lane * 8;
}

// ---------------------------------------------------------------------------
// pack_x_cbias: z<784 -> pack_x(gb=z); else make_cbias2(blk=z-784). grid 1176.
// ---------------------------------------------------------------------------
__global__ __launch_bounds__(256) void pack_x_cbias(
    const float* __restrict__ x, unsigned short* __restrict__ xp,
    const float* __restrict__ na, const float* __restrict__ ha,
    const float* __restrict__ wa, const float* __restrict__ an,
    const float* __restrict__ ah, const float* __restrict__ aw,
    unsigned short* __restrict__ cb1t, unsigned short* __restrict__ cb2t) {
  __shared__ unsigned short xlds[64 * 200];
  int z = blockIdx.x;
  int tid = threadIdx.x;
  if (z < 784) {
    int gb = z;
    int lane = tid & 63, wv = tid >> 6;
    int lo = lane & 15, g = lane >> 4;
    int tok0 = gb * 64;
    for (int kh = 0; kh < 2; kh++) {
      if (kh) __syncthreads();
#pragma unroll
      for (int it = 0; it < 12; it++) {
        int idx = tid + it * 256;
        int tok = idx / 48, k4 = idx % 48;
        float4 f = *(const float4*)&x[(size_t)(tok0 + tok) * 384 + kh * 192 + k4 * 4];
        uint2 o;
        o.x = (unsigned)f2bf(f.x) | ((unsigned)f2bf(f.y) << 16);
        o.y = (unsigned)f2bf(f.z) | ((unsigned)f2bf(f.w) << 16);
        *(uint2*)&xlds[tok * 200 + k4 * 4] = o;
      }
      __syncthreads();
      for (int p = wv; p < 24; p += 4) {
        int ks = p >> 2, j = p & 3;
        uint4 v = *(const uint4*)&xlds[(j * 16 + lo) * 200 + ks * 32 + g * 8];
        *(uint4*)&xp[xp_off(gb, kh * 6 + ks, j, lane)] = v;
      }
    }
  } else {
    int blk = z - 784;
    int h = blk / 49, nc = blk % 49;
    int a = tid & 63, sub = tid >> 6;
    int ac = a < AGG ? a : AGG - 1;
    bool va = a < AGG;
    size_t hab = (size_t)h * AGG + ac;
#pragma unroll
    for (int i = 0; i < 16; i++) {
      int n = nc * 64 + i * 4 + sub;
      int r = n / WI, c = n % WI;
      float v1 = na[hab * NN + n] + ha[(h * HI + r) * AGG + ac] + wa[(h * WI + c) * AGG + ac];
      float v2 = an[hab * NN + n] + ah[hab * HI + r] + aw[hab * WI + c];
      size_t ob = ((size_t)h * NN + n) * 52;
      if (a < 52) {
        cb1t[ob + a] = va ? f2bf(v1) : (unsigned short)0;
        cb2t[ob + a] = va ? f2bf(v2) : (unsigned short)0;
      }
    }
  }
}

// ---------------------------------------------------------------------------
// pack_w: Wq (384x384) | Wkv (384x768) -> wp fragment-packed. grid 18.
// ---------------------------------------------------------------------------
__global__ __launch_bounds__(256) void pack_w(const float* __restrict__ Wq,
                                              const float* __restrict__ Wkv,
                                              unsigned short* __restrict__ wp) {
  __shared__ unsigned short wlds[64 * 392];
  int blk = blockIdx.x;
  int col0 = blk * 64;
  const float* src;
  int ncol, nloc;
  if (col0 < 384) { src = Wq; ncol = 384; nloc = col0; }
  else            { src = Wkv; ncol = 768; nloc = col0 - 384; }
  int tid = threadIdx.x;
  int lane = tid & 63, wv = tid >> 6;
  int lo = lane & 15, g = lane >> 4;

#pragma unroll
  for (int it = 0; it < 96; it++) {
    int idx = tid + it * 256;
    int k = idx >> 6, col = idx & 63;
    wlds[col * 392 + k] = f2bf(src[(size_t)k * ncol + nloc + col]);
  }
  __syncthreads();
  for (int p = wv; p < 48; p += 4) {
    int ks = p >> 2, i = p & 3;
    uint4 v = *(const uint4*)&wlds[(i * 16 + lo) * 392 + ks * 32 + g * 8];
    *(uint4*)&wp[wp_off(blk, ks, i, lane)] = v;
  }
}

// ---------------------------------------------------------------------------
// gemm_v4: qkv[50176][1152](bf16) = X @ W, fragment-direct. (unchanged)
// ---------------------------------------------------------------------------
__global__ __launch_bounds__(256, 2) void gemm_v4(const unsigned short* __restrict__ xp,
                                                  const unsigned short* __restrict__ wp,
                                                  unsigned short* __restrict__ Y) {
  const int tid = threadIdx.x;
  const int lane = tid & 63;
  const int wave = tid >> 6;
  const int lo = lane & 15, g = lane >> 4;
  const int wt2 = wave & 1;   // token half
  const int wn2 = wave >> 1;  // col half

  int wg = blockIdx.x;
  int xcd = wg & 7, idx8 = wg >> 3;
  const int sq = 220, sr = 4;
  int l = (xcd < sr ? xcd * (sq + 1) : sr * (sq + 1) + (xcd - sr) * sq) + idx8;
  int bx = l % 9, by = l / 9;

  const int gbb = by * 4 + wt2 * 2;
  const unsigned short* wbase = wp + wp_off(bx * 2 + wn2, 0, 0, lane);
  const unsigned short* xbase0 = xp + xp_off(gbb + 0, 0, 0, lane);
  const unsigned short* xbase1 = xp + xp_off(gbb + 1, 0, 0, lane);

  f32x4 acc[4][8];
#pragma unroll
  for (int i = 0; i < 4; i++)
#pragma unroll
    for (int jj = 0; jj < 8; jj++) acc[i][jj] = (f32x4)0.f;

  short8 wfA[4], xfA[8], wfB[4], xfB[8];

  auto loadF = [&](short8* wf, short8* xf, int ks) {
    const unsigned short* wptr = wbase + (size_t)ks * 2048;
#pragma unroll
    for (int i = 0; i < 4; i++) wf[i] = *(const short8*)(wptr + i * 512);
    const unsigned short* x0 = xbase0 + (size_t)ks * 2048;
    const unsigned short* x1 = xbase1 + (size_t)ks * 2048;
#pragma unroll
    for (int j = 0; j < 4; j++) {
      xf[j] = *(const short8*)(x0 + j * 512);
      xf[4 + j] = *(const short8*)(x1 + j * 512);
    }
  };
  auto mfmaF = [&](short8* wf, short8* xf) {
    __builtin_amdgcn_s_setprio(1);
#pragma unroll
    for (int i = 0; i < 4; i++)
#pragma unroll
      for (int jj = 0; jj < 8; jj++)
        acc[i][jj] = __builtin_amdgcn_mfma_f32_16x16x32_bf16(wf[i], xf[jj], acc[i][jj], 0, 0, 0);
    __builtin_amdgcn_s_setprio(0);
  };

  loadF(wfA, xfA, 0);
#pragma unroll
  for (int kp = 0; kp < 6; kp++) {
    loadF(wfB, xfB, 2 * kp + 1);
    mfmaF(wfA, xfA);
    if (kp < 5) loadF(wfA, xfA, 2 * kp + 2);
    mfmaF(wfB, xfB);
  }

#pragma unroll
  for (int jj = 0; jj < 8; jj++) {
    int token = (gbb + (jj >> 2)) * 64 + (jj & 3) * 16 + lo;
#pragma unroll
    for (int i = 0; i < 4; i++) {
      int ncol = bx * 128 + wn2 * 64 + i * 16 + g * 4;
      uint2 o;
      o.x = (unsigned)f2bf(acc[i][jj][0]) | ((unsigned)f2bf(acc[i][jj][1]) << 16);
      o.y = (unsigned)f2bf(acc[i][jj][2]) | ((unsigned)f2bf(acc[i][jj][3]) << 16);
      *(uint2*)&Y[(size_t)token * QKVC + ncol] = o;
    }
  }
}

// ---------------------------------------------------------------------------
// prep2_fused: z<784 -> pack_vt(blk=z); else pool_agent(blk=z-784). grid 1568.
// ---------------------------------------------------------------------------
#define VSTR 396
__global__ __launch_bounds__(256) void prep2_fused(const unsigned short* __restrict__ qkv,
                                                   unsigned short* __restrict__ vtp,
                                                   unsigned short* __restrict__ agbf) {
  __shared__ unsigned short vlds[64 * VSTR];
  int z = blockIdx.x;
  int tid = threadIdx.x;
  if (z < 784) {
    int b = z / 49, chunk = z % 49;
    int lane = tid & 63, wv = tid >> 6;
    int lo = lane & 15, g = lane >> 4;
#pragma unroll
    for (int it = 0; it < 12; it++) {
      int idx = tid + it * 256;
      int t = idx / 48, d8 = idx % 48;
      short8 v = *(const short8*)&qkv[((size_t)b * NN + chunk * 64 + t) * QKVC + 768 + d8 * 8];
      *(uint2*)&vlds[t * VSTR + d8 * 8] = ((uint2*)&v)[0];
      *(uint2*)&vlds[t * VSTR + d8 * 8 + 4] = ((uint2*)&v)[1];
    }
    __syncthreads();
    int bh8 = b * 8;
#pragma unroll
    for (int p = 0; p < 12; p++) {
      int fid = wv * 12 + p;
      int h = fid / 6, rem = fid % 6, half = rem / 3, ntd = rem % 3;
      unsigned short tmp[8];
#pragma unroll
      for (int e = 0; e < 8; e++)
        tmp[e] = vlds[(half * 32 + g * 8 + e) * VSTR + h * 48 + ntd * 16 + lo];
      *(uint4*)&vtp[vtp_off(bh8 + h, chunk, half, ntd, lane)] = *(uint4*)tmp;
    }
  } else {
    int blk = z - 784;
    int b = blk / AGG, a = blk % AGG;
    int p1 = a / 7, p2 = a % 7;
    for (int c = tid; c < CC; c += 256) {
      float s = 0.f;
#pragma unroll
      for (int i = 0; i < 8; i++)
#pragma unroll
        for (int j = 0; j < 8; j++) {
          int n = (p1 * 8 + i) * WI + (p2 * 8 + j);
          s += bf2f(qkv[((size_t)b * NN + n) * QKVC + c]);
        }
      agbf[(size_t)blk * CC + c] = f2bf(s * (1.f / 64.f));
    }
  }
}

// ---------------------------------------------------------------------------
// attn_dwc_fused: z<512 agent_attn(z); z<1024 q_attn_psum(z-512);
// else dwc_rows(z-1024). grid 1920.
// ---------------------------------------------------------------------------
__global__ __launch_bounds__(256) void attn_dwc_fused(
    const unsigned short* __restrict__ qkv, const unsigned short* __restrict__ agbf,
    const unsigned short* __restrict__ cb1t, const unsigned short* __restrict__ cb2t,
    const unsigned short* __restrict__ vtp, float* __restrict__ lpart,
    float* __restrict__ avpart, float* __restrict__ opart,
    float* __restrict__ rowsum, float* __restrict__ edge0,
    float* __restrict__ edge1) {
  __shared__ __align__(16) unsigned short pT[4][64 * 72];
  __shared__ float ldsAV[AGG * 48];
  __shared__ float ldsL[AGG];

  int z = blockIdx.x;
  int tid = threadIdx.x, lane = tid & 63, wv = tid >> 6;
  int lo = lane & 15, g = lane >> 4;

  if (z < 512) {
    // ======================= agent attention (v5) =======================
    int s = z & 3;
    int h = (z >> 2) & 7;
    int b = z >> 5;
    int slot = s * 4 + wv;
    int cstart = (slot == 0) ? 0 : 3 * slot + 1;
    int ccount = (slot == 0) ? 4 : 3;
    int bh = b * 8 + h;

    for (int i = tid; i < AGG * 48; i += 256) ldsAV[i] = 0.f;
    if (tid < AGG) ldsL[tid] = 0.f;
    __syncthreads();

    short8 af0[4], af1[4];
#pragma unroll
    for (int mt = 0; mt < 4; mt++) {
      int a = mt * 16 + lo;
      int ac = a < AGG ? a : AGG - 1;
      const unsigned short* p = agbf + ((size_t)b * AGG + ac) * CC + h * 48;
      af0[mt] = *(const short8*)(p + g * 8);
      if (g < 2) af1[mt] = *(const short8*)(p + 32 + g * 8);
      else { short8 zz = {0, 0, 0, 0, 0, 0, 0, 0}; af1[mt] = zz; }
    }

    f32x4 acc2[4][3];
#pragma unroll
    for (int mt = 0; mt < 4; mt++)
#pragma unroll
      for (int ntd = 0; ntd < 3; ntd++) acc2[mt][ntd] = (f32x4)0.f;
    float lacc[4][4];
#pragma unroll
    for (int mt = 0; mt < 4; mt++)
#pragma unroll
      for (int r = 0; r < 4; r++) lacc[mt][r] = 0.f;

    for (int ci = 0; ci < ccount; ci++) {
      int chunk = cstart + ci;
      int nb = chunk * 64;

      short8 kf0[4], kf1[4];
#pragma unroll
      for (int nt = 0; nt < 4; nt++) {
        const unsigned short* kp = qkv + ((size_t)b * NN + nb + nt * 16 + lo) * QKVC + 384 + h * 48;
        kf0[nt] = *(const short8*)(kp + g * 8);
        if (g < 2) kf1[nt] = *(const short8*)(kp + 32 + g * 8);
        else { short8 zz = {0, 0, 0, 0, 0, 0, 0, 0}; kf1[nt] = zz; }
      }
      ushort4 cbv[4][4];
#pragma unroll
      for (int mt = 0; mt < 4; mt++)
#pragma unroll
        for (int nt = 0; nt < 4; nt++)
          cbv[mt][nt] = *(const ushort4*)&cb2t[((size_t)h * NN + nb + nt * 16 + lo) * 52 + mt * 16 + g * 4];
      short8 vb0[3], vb1[3];
#pragma unroll
      for (int ntd = 0; ntd < 3; ntd++) {
        vb0[ntd] = *(const short8*)&vtp[vtp_off(bh, chunk, 0, ntd, lane)];
        vb1[ntd] = *(const short8*)&vtp[vtp_off(bh, chunk, 1, ntd, lane)];
      }

      f32x4 acc[4][4];
#pragma unroll
      for (int mt = 0; mt < 4; mt++)
#pragma unroll
        for (int nt = 0; nt < 4; nt++) acc[mt][nt] = (f32x4)0.f;
#pragma unroll
      for (int mt = 0; mt < 4; mt++)
#pragma unroll
        for (int nt = 0; nt < 4; nt++) {
          acc[mt][nt] = __builtin_amdgcn_mfma_f32_16x16x32_bf16(af0[mt], kf0[nt], acc[mt][nt], 0, 0, 0);
          acc[mt][nt] = __builtin_amdgcn_mfma_f32_16x16x32_bf16(af1[mt], kf1[nt], acc[mt][nt], 0, 0, 0);
        }

#pragma unroll
      for (int mt = 0; mt < 4; mt++)
#pragma unroll
        for (int nt = 0; nt < 4; nt++) {
          unsigned short cb4[4] = {cbv[mt][nt].x, cbv[mt][nt].y, cbv[mt][nt].z, cbv[mt][nt].w};
#pragma unroll
          for (int r = 0; r < 4; r++) {
            int a = mt * 16 + g * 4 + r;
            float e = 0.f;
            if (a < AGG) e = __expf(acc[mt][nt][r] * SCALE_F + bf2f(cb4[r]));
            acc[mt][nt][r] = e;
          }
        }
#pragma unroll
      for (int mt = 0; mt < 4; mt++)
#pragma unroll
        for (int r = 0; r < 4; r++)
          lacc[mt][r] += acc[mt][0][r] + acc[mt][1][r] + acc[mt][2][r] + acc[mt][3][r];
#pragma unroll
      for (int mt = 0; mt < 4; mt++)
#pragma unroll
        for (int nt = 0; nt < 4; nt++)
#pragma unroll
          for (int r = 0; r < 4; r++) {
            int a = mt * 16 + g * 4 + r;
            int t = nt * 16 + lo;
            pT[wv][a * 72 + t] = f2bf(acc[mt][nt][r]);
          }

      short8 pa0[4], pa1[4];
#pragma unroll
      for (int mt = 0; mt < 4; mt++) {
        const unsigned short* p = &pT[wv][(mt * 16 + lo) * 72 + g * 8];
        pa0[mt] = *(const short8*)p;
        pa1[mt] = *(const short8*)(p + 32);
      }
#pragma unroll
      for (int mt = 0; mt < 4; mt++)
#pragma unroll
        for (int ntd = 0; ntd < 3; ntd++) {
          acc2[mt][ntd] = __builtin_amdgcn_mfma_f32_16x16x32_bf16(pa0[mt], vb0[ntd], acc2[mt][ntd], 0, 0, 0);
          acc2[mt][ntd] = __builtin_amdgcn_mfma_f32_16x16x32_bf16(pa1[mt], vb1[ntd], acc2[mt][ntd], 0, 0, 0);
        }
    }

#pragma unroll
    for (int mt = 0; mt < 4; mt++)
#pragma unroll
      for (int r = 0; r < 4; r++) {
        float v = lacc[mt][r];
        v += __shfl_xor(v, 1); v += __shfl_xor(v, 2);
        v += __shfl_xor(v, 4); v += __shfl_xor(v, 8);
        if (lo == 0) {
          int a = mt * 16 + g * 4 + r;
          if (a < AGG) atomicAdd(&ldsL[a], v);
        }
      }
#pragma unroll
    for (int mt = 0; mt < 4; mt++)
#pragma unroll
      for (int ntd = 0; ntd < 3; ntd++)
#pragma unroll
        for (int r = 0; r < 4; r++) {
          int a = mt * 16 + g * 4 + r;
          if (a < AGG) atomicAdd(&ldsAV[a * 48 + ntd * 16 + lo], acc2[mt][ntd][r]);
        }
    __syncthreads();
    size_t pbase = (size_t)bh * 4 + s;
    for (int i = tid; i < AGG * 48; i += 256) avpart[pbase * 2352 + i] = ldsAV[i];
    if (tid < AGG) lpart[pbase * AGG + tid] = ldsL[tid];

  } else if (z < 1024) {
    // ======================= q attention (psum, v9) =======================
    int zz = z - 512;
    int s = zz & 3;
    int h = (zz >> 2) & 7;
    int b = zz >> 5;
    int slot = s * 4 + wv;
    int cstart = (slot == 0) ? 0 : 3 * slot + 1;
    int ccount = (slot == 0) ? 4 : 3;
    int bh = b * 8 + h;

    short8 af0[4], af1[4];
#pragma unroll
    for (int mt = 0; mt < 4; mt++) {
      int a = mt * 16 + lo;
      int ac = a < AGG ? a : AGG - 1;
      const unsigned short* p = agbf + ((size_t)b * AGG + ac) * CC + h * 48;
      af0[mt] = *(const short8*)(p + g * 8);
      if (g < 2) af1[mt] = *(const short8*)(p + 32 + g * 8);
      else { short8 zz2 = {0, 0, 0, 0, 0, 0, 0, 0}; af1[mt] = zz2; }
    }

    float psum[4][4];
#pragma unroll
    for (int mt = 0; mt < 4; mt++)
#pragma unroll
      for (int r = 0; r < 4; r++) psum[mt][r] = 0.f;

    for (int ci = 0; ci < ccount; ci++) {
      int nb = (cstart + ci) * 64;

      short8 qf0[4], qf1[4];
#pragma unroll
      for (int nt = 0; nt < 4; nt++) {
        const unsigned short* qp = qkv + ((size_t)b * NN + nb + nt * 16 + lo) * QKVC + h * 48;
        qf0[nt] = *(const short8*)(qp + g * 8);
        if (g < 2) qf1[nt] = *(const short8*)(qp + 32 + g * 8);
        else { short8 zz2 = {0, 0, 0, 0, 0, 0, 0, 0}; qf1[nt] = zz2; }
      }
      ushort4 cbv[4][4];
#pragma unroll
      for (int mt = 0; mt < 4; mt++)
#pragma unroll
        for (int nt = 0; nt < 4; nt++)
          cbv[mt][nt] = *(const ushort4*)&cb1t[((size_t)h * NN + nb + nt * 16 + lo) * 52 + mt * 16 + g * 4];

      f32x4 acc[4][4];
#pragma unroll
      for (int mt = 0; mt < 4; mt++)
#pragma unroll
        for (int nt = 0; nt < 4; nt++) acc[mt][nt] = (f32x4)0.f;
#pragma unroll
      for (int mt = 0; mt < 4; mt++)
#pragma unroll
        for (int nt = 0; nt < 4; nt++) {
          acc[mt][nt] = __builtin_amdgcn_mfma_f32_16x16x32_bf16(af0[mt], qf0[nt], acc[mt][nt], 0, 0, 0);
          acc[mt][nt] = __builtin_amdgcn_mfma_f32_16x16x32_bf16(af1[mt], qf1[nt], acc[mt][nt], 0, 0, 0);
        }

#pragma unroll
      for (int nt = 0; nt < 4; nt++) {
        float lsum = 0.f;
#pragma unroll
        for (int mt = 0; mt < 4; mt++) {
          unsigned short cb4[4] = {cbv[mt][nt].x, cbv[mt][nt].y, cbv[mt][nt].z, cbv[mt][nt].w};
#pragma unroll
          for (int r = 0; r < 4; r++) {
            int a = mt * 16 + g * 4 + r;
            float e = 0.f;
            if (a < AGG) e = __expf(acc[mt][nt][r] * SCALE_F + bf2f(cb4[r]));
            acc[mt][nt][r] = e;
            lsum += e;
          }
        }
        lsum += __shfl_xor(lsum, 16);
        lsum += __shfl_xor(lsum, 32);
        float inv = 1.f / lsum;
#pragma unroll
        for (int mt = 0; mt < 4; mt++)
#pragma unroll
          for (int r = 0; r < 4; r++)
            psum[mt][r] += acc[mt][nt][r] * inv;
      }
    }

    size_t pbase = (size_t)bh * 16 + slot;
#pragma unroll
    for (int mt = 0; mt < 4; mt++)
#pragma unroll
      for (int r = 0; r < 4; r++) {
        float v = psum[mt][r];
        v += __shfl_xor(v, 1); v += __shfl_xor(v, 2);
        v += __shfl_xor(v, 4); v += __shfl_xor(v, 8);
        int a = mt * 16 + g * 4 + r;
        if (lo == 0 && a < AGG) opart[pbase * 52 + a] = v;
      }

  } else {
    // ======================= dwc rows =======================
    int zz = z - 1024;
    int b = zz / HI, r = zz % HI;
    for (int c = tid; c < CC; c += 256) {
      const unsigned short* base = qkv + ((size_t)b * NN + (size_t)r * WI) * QKVC + 768 + c;
      float sum = 0.f, e0v = 0.f, e1v = 0.f;
      for (int w = 0; w < WI; w++) {
        float v = bf2f(base[(size_t)w * QKVC]);
        sum += v;
        if (w == 0) e0v = v;
        if (w == WI - 1) e1v = v;
      }
      rowsum[(size_t)zz * CC + c] = sum;
      edge0[(size_t)zz * CC + c] = e0v;
      edge1[(size_t)zz * CC + c] = e1v;
    }
  }
}

// ---------------------------------------------------------------------------
// av_normalize4: merge 4 partials, divide, emit fp32 av[bh][49][48].
// ---------------------------------------------------------------------------
__global__ __launch_bounds__(256) void av_normalize4(const float* __restrict__ lpart,
                                                     const float* __restrict__ avpart,
                                                     float* __restrict__ av) {
  int bh = blockIdx.x;
  int tid = threadIdx.x;
  __shared__ float linv[AGG];
  if (tid < AGG) {
    float l = 0.f;
#pragma unroll
    for (int s = 0; s < 4; s++) l += lpart[((size_t)bh * 4 + s) * AGG + tid];
    linv[tid] = 1.f / l;
  }
  __syncthreads();
  for (int idx = tid; idx < AGG * 48; idx += 256) {
    int a = idx / 48;
    float v = 0.f;
#pragma unroll
    for (int s = 0; s < 4; s++) v += avpart[((size_t)bh * 4 + s) * 2352 + idx];
    av[(size_t)bh * 2352 + idx] = v * linv[a];
  }
}

// pass 2a — partial combine over 8-row chunks. grid (16*7) x 384.
__global__ __launch_bounds__(384) void dwc_combine1(const float* __restrict__ rowsum,
                                                    const float* __restrict__ edge0,
                                                    const float* __restrict__ edge1,
                                                    float* __restrict__ dpart,
                                                    float* __restrict__ dedge) {
  int z = blockIdx.x;
  int b = z / 7, rc = z % 7;
  int c = threadIdx.x;
  float T = 0.f, C0 = 0.f, C55 = 0.f;
#pragma unroll
  for (int rr = 0; rr < 8; rr++) {
    int r = rc * 8 + rr;
    size_t idx = ((size_t)(b * HI + r)) * CC + c;
    float rs = rowsum[idx], a0 = edge0[idx], a1 = edge1[idx];
    T += rs; C0 += a0; C55 += a1;
    if (r == 0) {
      dedge[((size_t)b * 6 + 0) * CC + c] = rs;
      dedge[((size_t)b * 6 + 1) * CC + c] = a0;
      dedge[((size_t)b * 6 + 2) * CC + c] = a1;
    }
    if (r == HI - 1) {
      dedge[((size_t)b * 6 + 3) * CC + c] = rs;
      dedge[((size_t)b * 6 + 4) * CC + c] = a0;
      dedge[((size_t)b * 6 + 5) * CC + c] = a1;
    }
  }
  size_t pb = ((size_t)(b * 7 + rc) * 3) * CC + c;
  dpart[pb] = T;
  dpart[pb + CC] = C0;
  dpart[pb + 2 * CC] = C55;
}

// ---------------------------------------------------------------------------
// head_pre: pre[b][k] = (dwc(k) + attn(k))/NN + dwc_b, where
// attn(k) = sum_a psum[h(k)][a] * av[b,h(k)][a][d(k)]. grid 16 x 384.
// ---------------------------------------------------------------------------
__global__ __launch_bounds__(384) void head_pre(const float* __restrict__ dpart,
                                                const float* __restrict__ dedge,
                                                const float* __restrict__ opart,
                                                const float* __restrict__ av,
                                                const float* __restrict__ w,
                                                const float* __restrict__ dwc_b,
                                                float* __restrict__ pre) {
  int b = blockIdx.x;
  int k = threadIdx.x;
  __shared__ float psums[HDS][AGG];
  for (int idx = k; idx < HDS * AGG; idx += 384) {
    int hh = idx / AGG, a = idx % AGG;
    float v = 0.f;
#pragma unroll
    for (int s = 0; s < 16; s++)
      v += opart[(((size_t)(b * 8 + hh) * 16) + s) * 52 + a];
    psums[hh][a] = v;
  }
  __syncthreads();

  float T = 0.f, C0 = 0.f, C55 = 0.f;
#pragma unroll
  for (int rc = 0; rc < 7; rc++) {
    size_t pb = ((size_t)(b * 7 + rc) * 3) * CC + k;
    T += dpart[pb];
    C0 += dpart[pb + CC];
    C55 += dpart[pb + 2 * CC];
  }
  float R0 = dedge[((size_t)b * 6 + 0) * CC + k];
  float v00 = dedge[((size_t)b * 6 + 1) * CC + k];
  float v0W = dedge[((size_t)b * 6 + 2) * CC + k];
  float R55 = dedge[((size_t)b * 6 + 3) * CC + k];
  float vH0 = dedge[((size_t)b * 6 + 4) * CC + k];
  float vHW = dedge[((size_t)b * 6 + 5) * CC + k];
  float dwcsum = 0.f;
#pragma unroll
  for (int i = 0; i < 3; i++) {
    int di = i - 1;
#pragma unroll
    for (int j = 0; j < 3; j++) {
      int dj = j - 1;
      float S = T;
      if (di == 1) S -= R0; else if (di == -1) S -= R55;
      if (dj == 1) S -= C0; else if (dj == -1) S -= C55;
      if (di != 0 && dj != 0)
        S += (di == 1) ? ((dj == 1) ? v00 : v0W) : ((dj == 1) ? vH0 : vHW);
      dwcsum += w[k * 9 + i * 3 + j] * S;
    }
  }

  int hh = k / 48, dd = k % 48;
  const float* avb = av + ((size_t)(b * 8 + hh)) * 2352 + dd;
  float attn = 0.f;
#pragma unroll 7
  for (int a = 0; a < AGG; a++) attn += psums[hh][a] * avb[(size_t)a * 48];
  pre[(size_t)b * CC + k] = (dwcsum + attn) * (1.f / (float)NN) + dwc_b[k];
}

// head_proj_part: K=384 split x6. waves = 16b x 6oc x 6kc = 576; grid 144.
__global__ __launch_bounds__(256) void head_proj_part(
    const float* __restrict__ pre, const float* __restrict__ Wproj,
    float* __restrict__ pjpart) {
  int w = blockIdx.x * 4 + (threadIdx.x >> 6);
  int lane = threadIdx.x & 63;
  int b = w / 36, rem = w % 36;
  int oc = rem / 6, kc = rem % 6;
  int o = oc * 64 + lane;
  const float* pb = pre + (size_t)b * CC + kc * 64;
  const float* wp2 = Wproj + (size_t)(kc * 64) * CC + o;
  float s = 0.f;
#pragma unroll 16
  for (int k = 0; k < 64; k++) s += pb[k] * wp2[(size_t)k * CC];
  pjpart[((size_t)(b * 6 + kc)) * CC + o] = s;
}

__global__ __launch_bounds__(384) void head_ln6(const float* __restrict__ pjpart,
                                                const float* __restrict__ bproj,
                                                const float* __restrict__ ln_g,
                                                const float* __restrict__ ln_b,
                                                float* __restrict__ h0) {
  int b = blockIdx.x;
  int tid = threadIdx.x;
  __shared__ float red[8];
  float v = bproj[tid];
#pragma unroll
  for (int kc = 0; kc < 6; kc++) v += pjpart[((size_t)(b * 6 + kc)) * CC + tid];
  float m;
  {
    float s = v;
#pragma unroll
    for (int o = 32; o > 0; o >>= 1) s += __shfl_down(s, o);
    if ((tid & 63) == 0) red[tid >> 6] = s;
    __syncthreads();
    if (tid == 0) {
      float t = 0.f;
      for (int i = 0; i < 6; i++) t += red[i];
      red[6] = t * (1.f / (float)CC);
    }
    __syncthreads();
    m = red[6];
  }
  float dv = v - m;
  __syncthreads();
  float var;
  {
    float s = dv * dv;
#pragma unroll
    for (int o = 32; o > 0; o >>= 1) s += __shfl_down(s, o);
    if ((tid & 63) == 0) red[tid >> 6] = s;
    __syncthreads();
    if (tid == 0) {
      float t = 0.f;
      for (int i = 0; i < 6; i++) t += red[i];
      red[7] = t * (1.f / (float)CC);
    }
    __syncthreads();
    var = red[7];
  }
  h0[(size_t)b * CC + tid] = dv * rsqrtf(var + 1e-5f) * ln_g[tid] + ln_b[tid];
}

__global__ __launch_bounds__(256) void head_mlp1_part(
    const float* __restrict__ h0, const float* __restrict__ W1,
    float* __restrict__ h1part) {
  int w = blockIdx.x * 4 + (threadIdx.x >> 6);
  int lane = threadIdx.x & 63;
  int b = w / 72, rem = w % 72;
  int oc = rem / 6, kc = rem % 6;
  int o = oc * 64 + lane;
  const float* hb = h0 + (size_t)b * CC + kc * 64;
  const float* wp2 = W1 + (size_t)(kc * 64) * (2 * CC) + o;
  float s = 0.f;
#pragma unroll 16
  for (int k = 0; k < 64; k++) s += hb[k] * wp2[(size_t)k * (2 * CC)];
  h1part[((size_t)(b * 6 + kc)) * (2 * CC) + o] = s;
}

__global__ __launch_bounds__(256) void head_mlp1_red(const float* __restrict__ h1part,
                                                     const float* __restrict__ b1,
                                                     float* __restrict__ h1) {
  int b = blockIdx.x;
  for (int o = threadIdx.x; o < 2 * CC; o += 256) {
    float s = b1[o];
#pragma unroll
    for (int kc = 0; kc < 6; kc++) s += h1part[((size_t)(b * 6 + kc)) * (2 * CC) + o];
    h1[(size_t)b * (2 * CC) + o] = 0.5f * s * (1.f + erff(s * 0.70710678118654752f));
  }
}

__global__ __launch_bounds__(256) void head_mlp2_part(
    const float* __restrict__ h1, const float* __restrict__ W2,
    float* __restrict__ o2part) {
  int w = blockIdx.x * 4 + (threadIdx.x >> 6);
  int lane = threadIdx.x & 63;
  int b = w / 192, rem = w % 192;
  int oc = rem / 12, kc = rem % 12;
  int o = oc * 64 + lane;
  int ocl = o < OUTD ? o : OUTD - 1;
  const float* hb = h1 + (size_t)b * (2 * CC) + kc * 64;
  const float* wp2 = W2 + (size_t)(kc * 64) * OUTD + ocl;
  float s = 0.f;
#pragma unroll 16
  for (int k = 0; k < 64; k++) s += hb[k] * wp2[(size_t)k * OUTD];
  o2part[((size_t)(b * 12 + kc)) * 1024 + o] = s;
}

__global__ __launch_bounds__(256) void head_out(const float* __restrict__ o2part,
                                                const float* __restrict__ b2,
                                                float* __restrict__ out) {
  int b = blockIdx.x;
  for (int o = threadIdx.x; o < OUTD; o += 256) {
    float s = b2[o];
#pragma unroll
    for (int kc = 0; kc < 12; kc++) s += o2part[((size_t)(b * 12 + kc)) * 1024 + o];
    out[(size_t)b * OUTD + o] = s;
  }
}

// ---------------------------------------------------------------------------
extern "C" void kernel_launch(void* const* d_in, const int* in_sizes, int n_in,
                              void* d_out, int out_size, void* d_ws,
                              size_t ws_size, hipStream_t stream) {
  const float* x = (const float*)d_in[0];
  const float* Wq = (const float*)d_in[1];
  const float* Wkv = (const float*)d_in[2];
  const float* an_bias = (const float*)d_in[3];
  const float* na_bias = (const float*)d_in[4];
  const float* ah_bias = (const float*)d_in[5];
  const float* aw_bias = (const float*)d_in[6];
  const float* ha_bias = (const float*)d_in[7];
  const float* wa_bias = (const float*)d_in[8];
  const float* dwc_w = (const float*)d_in[9];
  const float* dwc_b = (const float*)d_in[10];
  const float* Wproj = (const float*)d_in[11];
  const float* bproj = (const float*)d_in[12];
  const float* ln_g = (const float*)d_in[13];
  const float* ln_b = (const float*)d_in[14];
  const float* W1 = (const float*)d_in[15];
  const float* b1 = (const float*)d_in[16];
  const float* W2 = (const float*)d_in[17];
  const float* b2 = (const float*)d_in[18];
  float* out = (float*)d_out;

  const size_t M = (size_t)BB * NN;  // 50176
  char* wsp = (char*)d_ws;
  unsigned short* xp = (unsigned short*)wsp;    // reused as vtp after gemm
  unsigned short* vtp = xp;
  wsp += M * CC * 2;
  unsigned short* wpb = (unsigned short*)wsp;   wsp += (size_t)QKVC * CC * 2;
  unsigned short* qkv = (unsigned short*)wsp;   wsp += M * QKVC * 2;
  unsigned short* agbf = (unsigned short*)wsp;  wsp += (size_t)784 * CC * 2;
  unsigned short* cb1t = (unsigned short*)wsp;  wsp += (size_t)HDS * NN * 52 * 2;
  unsigned short* cb2t = (unsigned short*)wsp;  wsp += (size_t)HDS * NN * 52 * 2;
  float* lpart = (float*)wsp;                   wsp += (size_t)128 * 4 * AGG * 4;
  float* avpart = (float*)wsp;                  wsp += (size_t)128 * 4 * 2352 * 4;
  float* av = (float*)wsp;                      wsp += (size_t)128 * 2352 * 4;
  float* opart = (float*)wsp;                   wsp += (size_t)128 * 16 * 52 * 4;
  float* rowsum = (float*)wsp;                  wsp += (size_t)BB * HI * CC * 4;
  float* edge0 = (float*)wsp;                   wsp += (size_t)BB * HI * CC * 4;
  float* edge1 = (float*)wsp;                   wsp += (size_t)BB * HI * CC * 4;
  float* dpart = (float*)wsp;                   wsp += (size_t)BB * 7 * 3 * CC * 4;
  float* dedge = (float*)wsp;                   wsp += (size_t)BB * 6 * CC * 4;
  float* pre = (float*)wsp;                     wsp += (size_t)BB * CC * 4;
  float* pjpart = (float*)wsp;                  wsp += (size_t)BB * 6 * CC * 4;
  float* h0b = (float*)wsp;                     wsp += (size_t)BB * CC * 4;
  float* h1part = (float*)wsp;                  wsp += (size_t)BB * 6 * 2 * CC * 4;
  float* h1b = (float*)wsp;                     wsp += (size_t)BB * 2 * CC * 4;
  float* o2part = (float*)wsp;                  wsp += (size_t)BB * 12 * 1024 * 4;

  dim3 blk256(256);
  hipLaunchKernelGGL(pack_x_cbias, dim3(1176), blk256, 0, stream, x, xp,
                     na_bias, ha_bias, wa_bias, an_bias, ah_bias, aw_bias,
                     cb1t, cb2t);
  hipLaunchKernelGGL(pack_w, dim3(18), blk256, 0, stream, Wq, Wkv, wpb);
  hipLaunchKernelGGL(gemm_v4, dim3(1764), blk256, 0, stream, xp, wpb, qkv);
  // xp dead from here; vtp aliases it
  hipLaunchKernelGGL(prep2_fused, dim3(1568), blk256, 0, stream, qkv, vtp, agbf);
  hipLaunchKernelGGL(attn_dwc_fused, dim3(1920), blk256, 0, stream, qkv, agbf,
                     cb1t, cb2t, vtp, lpart, avpart, opart, rowsum, edge0, edge1);
  hipLaunchKernelGGL(av_normalize4, dim3(BB * HDS), blk256, 0, stream, lpart,
                     avpart, av);
  hipLaunchKernelGGL(dwc_combine1, dim3(BB * 7), dim3(384), 0, stream, rowsum,
                     edge0, edge1, dpart, dedge);
  hipLaunchKernelGGL(head_pre, dim3(BB), dim3(384), 0, stream, dpart, dedge,
                     opart, av, dwc_w, dwc_b, pre);
  hipLaunchKernelGGL(head_proj_part, dim3(144), blk256, 0, stream, pre, Wproj, pjpart);
  hipLaunchKernelGGL(head_ln6, dim3(BB), dim3(384), 0, stream, pjpart, bproj,
                     ln_g, ln_b, h0b);
  hipLaunchKernelGGL(head_mlp1_part, dim3(288), blk256, 0, stream, h0b, W1, h1part);
  hipLaunchKernelGGL(head_mlp1_red, dim3(BB), blk256, 0, stream, h1part, b1, h1b);
  hipLaunchKernelGGL(head_mlp2_part, dim3(768), blk256, 0, stream, h1b, W2, o2part);
  hipLaunchKernelGGL(head_out, dim3(BB), blk256, 0, stream, o2part, b2, out);
}

// Round 18
// 265.467 us; speedup vs baseline: 1.0243x; 1.0243x over previous
//
#include <hip/hip_runtime.h>
#include <hip/hip_bf16.h>
#include <math.h>

// Problem constants
#define BB 16
#define NN 3136
#define CC 384
#define HDS 8
#define DHH 48
#define AGG 49
#define HI 56
#define WI 56
#define OUTD 1000
#define SCALE_F 0.14433756729740643f  // 48^-0.5
#define QKVC 1152                     // q|k|v column stride

typedef __attribute__((ext_vector_type(8))) short short8;
typedef __attribute__((ext_vector_type(4))) float f32x4;

__device__ __forceinline__ float bf2f(unsigned short u) {
  union { unsigned u32; float f; } x;
  x.u32 = ((unsigned)u) << 16;
  return x.f;
}
__device__ __forceinline__ unsigned short f2bf(float f) {
  union { float f; unsigned u; } x;
  x.f = f;
  unsigned u = x.u;
  unsigned r = (u + 0x7fffu + ((u >> 16) & 1u)) >> 16;
  return (unsigned short)r;
}

// Fragment-pack offset functions (shared by producer & consumer).
__device__ __forceinline__ size_t xp_off(int gb, int ks, int j, int lane) {
  return ((((size_t)gb * 12 + ks) * 4 + j) * 64 + lane) * 8;
}
__device__ __forceinline__ size_t wp_off(int blk, int ks, int i, int lane) {
  return ((((size_t)blk * 12 + ks) * 4 + i) * 64 + lane) * 8;
}
// vtp: V^T fragments: [bh][chunk49][half2][ntd3][lane64][8]
__device__ __forceinline__ size_t vtp_off(int bh, int chunk, int half, int ntd, int lane) {
  return ((((size_t)bh * 49 + chunk) * 2 + half) * 3 + ntd) * 512 + lane * 8;
}

// ---------------------------------------------------------------------------
// pack_x: x (fp32 [50176][384]) -> xp (bf16 fragment-packed). grid 784.
// ---------------------------------------------------------------------------
__global__ __launch_bounds__(256) void pack_x(const float* __restrict__ x,
                                              unsigned short* __restrict__ xp) {
  __shared__ unsigned short xlds[64 * 200];
  int gb = blockIdx.x;
  int tid = threadIdx.x;
  int lane = tid & 63, wv = tid >> 6;
  int lo = lane & 15, g = lane >> 4;
  int tok0 = gb * 64;

  for (int kh = 0; kh < 2; kh++) {
    if (kh) __syncthreads();
#pragma unroll
    for (int it = 0; it < 12; it++) {
      int idx = tid + it * 256;
      int tok = idx / 48, k4 = idx % 48;
      float4 f = *(const float4*)&x[(size_t)(tok0 + tok) * 384 + kh * 192 + k4 * 4];
      uint2 o;
      o.x = (unsigned)f2bf(f.x) | ((unsigned)f2bf(f.y) << 16);
      o.y = (unsigned)f2bf(f.z) | ((unsigned)f2bf(f.w) << 16);
      *(uint2*)&xlds[tok * 200 + k4 * 4] = o;
    }
    __syncthreads();
    for (int p = wv; p < 24; p += 4) {
      int ks = p >> 2, j = p & 3;
      uint4 v = *(const uint4*)&xlds[(j * 16 + lo) * 200 + ks * 32 + g * 8];
      *(uint4*)&xp[xp_off(gb, kh * 6 + ks, j, lane)] = v;
    }
  }
}

// ---------------------------------------------------------------------------
// pack_w: Wq (384x384) | Wkv (384x768) -> wp fragment-packed. grid 18.
// ---------------------------------------------------------------------------
__global__ __launch_bounds__(256) void pack_w(const float* __restrict__ Wq,
                                              const float* __restrict__ Wkv,
                                              unsigned short* __restrict__ wp) {
  __shared__ unsigned short wlds[64 * 392];
  int blk = blockIdx.x;
  int col0 = blk * 64;
  const float* src;
  int ncol, nloc;
  if (col0 < 384) { src = Wq; ncol = 384; nloc = col0; }
  else            { src = Wkv; ncol = 768; nloc = col0 - 384; }
  int tid = threadIdx.x;
  int lane = tid & 63, wv = tid >> 6;
  int lo = lane & 15, g = lane >> 4;

#pragma unroll
  for (int it = 0; it < 96; it++) {
    int idx = tid + it * 256;
    int k = idx >> 6, col = idx & 63;
    wlds[col * 392 + k] = f2bf(src[(size_t)k * ncol + nloc + col]);
  }
  __syncthreads();
  for (int p = wv; p < 48; p += 4) {
    int ks = p >> 2, i = p & 3;
    uint4 v = *(const uint4*)&wlds[(i * 16 + lo) * 392 + ks * 32 + g * 8];
    *(uint4*)&wp[wp_off(blk, ks, i, lane)] = v;
  }
}

// ---------------------------------------------------------------------------
// gemm_v4: qkv[50176][1152](bf16) = X @ W, fragment-direct. (unchanged)
// ---------------------------------------------------------------------------
__global__ __launch_bounds__(256, 2) void gemm_v4(const unsigned short* __restrict__ xp,
                                                  const unsigned short* __restrict__ wp,
                                                  unsigned short* __restrict__ Y) {
  const int tid = threadIdx.x;
  const int lane = tid & 63;
  const int wave = tid >> 6;
  const int lo = lane & 15, g = lane >> 4;
  const int wt2 = wave & 1;   // token half
  const int wn2 = wave >> 1;  // col half

  int wg = blockIdx.x;
  int xcd = wg & 7, idx8 = wg >> 3;
  const int sq = 220, sr = 4;
  int l = (xcd < sr ? xcd * (sq + 1) : sr * (sq + 1) + (xcd - sr) * sq) + idx8;
  int bx = l % 9, by = l / 9;

  const int gbb = by * 4 + wt2 * 2;
  const unsigned short* wbase = wp + wp_off(bx * 2 + wn2, 0, 0, lane);
  const unsigned short* xbase0 = xp + xp_off(gbb + 0, 0, 0, lane);
  const unsigned short* xbase1 = xp + xp_off(gbb + 1, 0, 0, lane);

  f32x4 acc[4][8];
#pragma unroll
  for (int i = 0; i < 4; i++)
#pragma unroll
    for (int jj = 0; jj < 8; jj++) acc[i][jj] = (f32x4)0.f;

  short8 wfA[4], xfA[8], wfB[4], xfB[8];

  auto loadF = [&](short8* wf, short8* xf, int ks) {
    const unsigned short* wptr = wbase + (size_t)ks * 2048;
#pragma unroll
    for (int i = 0; i < 4; i++) wf[i] = *(const short8*)(wptr + i * 512);
    const unsigned short* x0 = xbase0 + (size_t)ks * 2048;
    const unsigned short* x1 = xbase1 + (size_t)ks * 2048;
#pragma unroll
    for (int j = 0; j < 4; j++) {
      xf[j] = *(const short8*)(x0 + j * 512);
      xf[4 + j] = *(const short8*)(x1 + j * 512);
    }
  };
  auto mfmaF = [&](short8* wf, short8* xf) {
    __builtin_amdgcn_s_setprio(1);
#pragma unroll
    for (int i = 0; i < 4; i++)
#pragma unroll
      for (int jj = 0; jj < 8; jj++)
        acc[i][jj] = __builtin_amdgcn_mfma_f32_16x16x32_bf16(wf[i], xf[jj], acc[i][jj], 0, 0, 0);
    __builtin_amdgcn_s_setprio(0);
  };

  loadF(wfA, xfA, 0);
#pragma unroll
  for (int kp = 0; kp < 6; kp++) {
    loadF(wfB, xfB, 2 * kp + 1);
    mfmaF(wfA, xfA);
    if (kp < 5) loadF(wfA, xfA, 2 * kp + 2);
    mfmaF(wfB, xfB);
  }

#pragma unroll
  for (int jj = 0; jj < 8; jj++) {
    int token = (gbb + (jj >> 2)) * 64 + (jj & 3) * 16 + lo;
#pragma unroll
    for (int i = 0; i < 4; i++) {
      int ncol = bx * 128 + wn2 * 64 + i * 16 + g * 4;
      uint2 o;
      o.x = (unsigned)f2bf(acc[i][jj][0]) | ((unsigned)f2bf(acc[i][jj][1]) << 16);
      o.y = (unsigned)f2bf(acc[i][jj][2]) | ((unsigned)f2bf(acc[i][jj][3]) << 16);
      *(uint2*)&Y[(size_t)token * QKVC + ncol] = o;
    }
  }
}

// ---------------------------------------------------------------------------
// make_cbias2: transposed bf16 biases cb1t/cb2t [h][n][52].
// ---------------------------------------------------------------------------
__global__ __launch_bounds__(256) void make_cbias2(
    const float* __restrict__ na, const float* __restrict__ ha,
    const float* __restrict__ wa, const float* __restrict__ an,
    const float* __restrict__ ah, const float* __restrict__ aw,
    unsigned short* __restrict__ cb1t, unsigned short* __restrict__ cb2t) {
  int blk = blockIdx.x;
  int h = blk / 49, nc = blk % 49;
  int a = threadIdx.x & 63, sub = threadIdx.x >> 6;
  int ac = a < AGG ? a : AGG - 1;
  bool va = a < AGG;
  size_t hab = (size_t)h * AGG + ac;
#pragma unroll
  for (int i = 0; i < 16; i++) {
    int n = nc * 64 + i * 4 + sub;
    int r = n / WI, c = n % WI;
    float v1 = na[hab * NN + n] + ha[(h * HI + r) * AGG + ac] + wa[(h * WI + c) * AGG + ac];
    float v2 = an[hab * NN + n] + ah[hab * HI + r] + aw[hab * WI + c];
    size_t ob = ((size_t)h * NN + n) * 52;
    if (a < 52) {
      cb1t[ob + a] = va ? f2bf(v1) : (unsigned short)0;
      cb2t[ob + a] = va ? f2bf(v2) : (unsigned short)0;
    }
  }
}

// ---------------------------------------------------------------------------
// pack_vt: V (bf16 in qkv) -> V^T MFMA B-fragments in global. grid BB*49.
// ---------------------------------------------------------------------------
#define VSTR 396
__global__ __launch_bounds__(256) void pack_vt(const unsigned short* __restrict__ qkv,
                                               unsigned short* __restrict__ vtp) {
  __shared__ unsigned short vlds[64 * VSTR];
  int blk = blockIdx.x;  // b*49 + chunk
  int b = blk / 49, chunk = blk % 49;
  int tid = threadIdx.x, lane = tid & 63, wv = tid >> 6;
  int lo = lane & 15, g = lane >> 4;

#pragma unroll
  for (int it = 0; it < 12; it++) {
    int idx = tid + it * 256;
    int t = idx / 48, d8 = idx % 48;
    short8 v = *(const short8*)&qkv[((size_t)b * NN + chunk * 64 + t) * QKVC + 768 + d8 * 8];
    *(uint2*)&vlds[t * VSTR + d8 * 8] = ((uint2*)&v)[0];
    *(uint2*)&vlds[t * VSTR + d8 * 8 + 4] = ((uint2*)&v)[1];
  }
  __syncthreads();
  int bh8 = b * 8;
#pragma unroll
  for (int p = 0; p < 12; p++) {
    int fid = wv * 12 + p;
    int h = fid / 6, rem = fid % 6, half = rem / 3, ntd = rem % 3;
    unsigned short tmp[8];
#pragma unroll
    for (int e = 0; e < 8; e++)
      tmp[e] = vlds[(half * 32 + g * 8 + e) * VSTR + h * 48 + ntd * 16 + lo];
    *(uint4*)&vtp[vtp_off(bh8 + h, chunk, half, ntd, lane)] = *(uint4*)tmp;
  }
}

// ---------------------------------------------------------------------------
// agent = pool(q) over 8x8 blocks -> bf16
// ---------------------------------------------------------------------------
__global__ __launch_bounds__(384) void pool_agent(const unsigned short* __restrict__ qkv,
                                                  unsigned short* __restrict__ agbf) {
  int blk = blockIdx.x;
  int b = blk / AGG, a = blk % AGG;
  int p1 = a / 7, p2 = a % 7;
  int c = threadIdx.x;
  float s = 0.f;
#pragma unroll
  for (int i = 0; i < 8; i++)
#pragma unroll
    for (int j = 0; j < 8; j++) {
      int n = (p1 * 8 + i) * WI + (p2 * 8 + j);
      s += bf2f(qkv[((size_t)b * NN + n) * QKVC + c]);
    }
  agbf[(size_t)blk * CC + c] = f2bf(s * (1.f / 64.f));
}

// ---------------------------------------------------------------------------
// Agent attention v5 (round-13 best): grid (b,h,s=4) = 512 blocks.
// ---------------------------------------------------------------------------
__global__ __launch_bounds__(256) void agent_attn_v5(
    const unsigned short* __restrict__ qkv, const unsigned short* __restrict__ agbf,
    const unsigned short* __restrict__ cb2t, const unsigned short* __restrict__ vtp,
    float* __restrict__ lpart, float* __restrict__ avpart) {
  int z = blockIdx.x;
  int s = z & 3;
  int h = (z >> 2) & 7;
  int b = z >> 5;
  int tid = threadIdx.x, lane = tid & 63, wv = tid >> 6;
  int lo = lane & 15, g = lane >> 4;
  int slot = s * 4 + wv;
  int cstart = (slot == 0) ? 0 : 3 * slot + 1;
  int ccount = (slot == 0) ? 4 : 3;
  int bh = b * 8 + h;

  __shared__ __align__(16) unsigned short pT[4][64 * 72];
  __shared__ float ldsAV[AGG * 48];
  __shared__ float ldsL[AGG];
  for (int i = tid; i < AGG * 48; i += 256) ldsAV[i] = 0.f;
  if (tid < AGG) ldsL[tid] = 0.f;
  __syncthreads();

  short8 af0[4], af1[4];
#pragma unroll
  for (int mt = 0; mt < 4; mt++) {
    int a = mt * 16 + lo;
    int ac = a < AGG ? a : AGG - 1;
    const unsigned short* p = agbf + ((size_t)b * AGG + ac) * CC + h * 48;
    af0[mt] = *(const short8*)(p + g * 8);
    if (g < 2) af1[mt] = *(const short8*)(p + 32 + g * 8);
    else { short8 zz = {0, 0, 0, 0, 0, 0, 0, 0}; af1[mt] = zz; }
  }

  f32x4 acc2[4][3];
#pragma unroll
  for (int mt = 0; mt < 4; mt++)
#pragma unroll
    for (int ntd = 0; ntd < 3; ntd++) acc2[mt][ntd] = (f32x4)0.f;
  float lacc[4][4];
#pragma unroll
  for (int mt = 0; mt < 4; mt++)
#pragma unroll
    for (int r = 0; r < 4; r++) lacc[mt][r] = 0.f;

  for (int ci = 0; ci < ccount; ci++) {
    int chunk = cstart + ci;
    int nb = chunk * 64;

    short8 kf0[4], kf1[4];
#pragma unroll
    for (int nt = 0; nt < 4; nt++) {
      const unsigned short* kp = qkv + ((size_t)b * NN + nb + nt * 16 + lo) * QKVC + 384 + h * 48;
      kf0[nt] = *(const short8*)(kp + g * 8);
      if (g < 2) kf1[nt] = *(const short8*)(kp + 32 + g * 8);
      else { short8 zz = {0, 0, 0, 0, 0, 0, 0, 0}; kf1[nt] = zz; }
    }
    ushort4 cbv[4][4];
#pragma unroll
    for (int mt = 0; mt < 4; mt++)
#pragma unroll
      for (int nt = 0; nt < 4; nt++)
        cbv[mt][nt] = *(const ushort4*)&cb2t[((size_t)h * NN + nb + nt * 16 + lo) * 52 + mt * 16 + g * 4];
    short8 vb0[3], vb1[3];
#pragma unroll
    for (int ntd = 0; ntd < 3; ntd++) {
      vb0[ntd] = *(const short8*)&vtp[vtp_off(bh, chunk, 0, ntd, lane)];
      vb1[ntd] = *(const short8*)&vtp[vtp_off(bh, chunk, 1, ntd, lane)];
    }

    f32x4 acc[4][4];
#pragma unroll
    for (int mt = 0; mt < 4; mt++)
#pragma unroll
      for (int nt = 0; nt < 4; nt++) acc[mt][nt] = (f32x4)0.f;
#pragma unroll
    for (int mt = 0; mt < 4; mt++)
#pragma unroll
      for (int nt = 0; nt < 4; nt++) {
        acc[mt][nt] = __builtin_amdgcn_mfma_f32_16x16x32_bf16(af0[mt], kf0[nt], acc[mt][nt], 0, 0, 0);
        acc[mt][nt] = __builtin_amdgcn_mfma_f32_16x16x32_bf16(af1[mt], kf1[nt], acc[mt][nt], 0, 0, 0);
      }

#pragma unroll
    for (int mt = 0; mt < 4; mt++)
#pragma unroll
      for (int nt = 0; nt < 4; nt++) {
        unsigned short cb4[4] = {cbv[mt][nt].x, cbv[mt][nt].y, cbv[mt][nt].z, cbv[mt][nt].w};
#pragma unroll
        for (int r = 0; r < 4; r++) {
          int a = mt * 16 + g * 4 + r;
          float e = 0.f;
          if (a < AGG) e = __expf(acc[mt][nt][r] * SCALE_F + bf2f(cb4[r]));
          acc[mt][nt][r] = e;
        }
      }
#pragma unroll
    for (int mt = 0; mt < 4; mt++)
#pragma unroll
      for (int r = 0; r < 4; r++)
        lacc[mt][r] += acc[mt][0][r] + acc[mt][1][r] + acc[mt][2][r] + acc[mt][3][r];
#pragma unroll
    for (int mt = 0; mt < 4; mt++)
#pragma unroll
      for (int nt = 0; nt < 4; nt++)
#pragma unroll
        for (int r = 0; r < 4; r++) {
          int a = mt * 16 + g * 4 + r;
          int t = nt * 16 + lo;
          pT[wv][a * 72 + t] = f2bf(acc[mt][nt][r]);
        }

    short8 pa0[4], pa1[4];
#pragma unroll
    for (int mt = 0; mt < 4; mt++) {
      const unsigned short* p = &pT[wv][(mt * 16 + lo) * 72 + g * 8];
      pa0[mt] = *(const short8*)p;
      pa1[mt] = *(const short8*)(p + 32);
    }
#pragma unroll
    for (int mt = 0; mt < 4; mt++)
#pragma unroll
      for (int ntd = 0; ntd < 3; ntd++) {
        acc2[mt][ntd] = __builtin_amdgcn_mfma_f32_16x16x32_bf16(pa0[mt], vb0[ntd], acc2[mt][ntd], 0, 0, 0);
        acc2[mt][ntd] = __builtin_amdgcn_mfma_f32_16x16x32_bf16(pa1[mt], vb1[ntd], acc2[mt][ntd], 0, 0, 0);
      }
  }

#pragma unroll
  for (int mt = 0; mt < 4; mt++)
#pragma unroll
    for (int r = 0; r < 4; r++) {
      float v = lacc[mt][r];
      v += __shfl_xor(v, 1); v += __shfl_xor(v, 2);
      v += __shfl_xor(v, 4); v += __shfl_xor(v, 8);
      if (lo == 0) {
        int a = mt * 16 + g * 4 + r;
        if (a < AGG) atomicAdd(&ldsL[a], v);
      }
    }
#pragma unroll
  for (int mt = 0; mt < 4; mt++)
#pragma unroll
    for (int ntd = 0; ntd < 3; ntd++)
#pragma unroll
      for (int r = 0; r < 4; r++) {
        int a = mt * 16 + g * 4 + r;
        if (a < AGG) atomicAdd(&ldsAV[a * 48 + ntd * 16 + lo], acc2[mt][ntd][r]);
      }
  __syncthreads();
  size_t pbase = (size_t)bh * 4 + s;
  for (int i = tid; i < AGG * 48; i += 256) avpart[pbase * 2352 + i] = ldsAV[i];
  if (tid < AGG) lpart[pbase * AGG + tid] = ldsL[tid];
}

// ---------------------------------------------------------------------------
// av_normalize4: merge 4 partials, divide, emit fp32 av[bh][49][48].
// ---------------------------------------------------------------------------
__global__ __launch_bounds__(256) void av_normalize4(const float* __restrict__ lpart,
                                                     const float* __restrict__ avpart,
                                                     float* __restrict__ av) {
  int bh = blockIdx.x;
  int tid = threadIdx.x;
  __shared__ float linv[AGG];
  if (tid < AGG) {
    float l = 0.f;
#pragma unroll
    for (int s = 0; s < 4; s++) l += lpart[((size_t)bh * 4 + s) * AGG + tid];
    linv[tid] = 1.f / l;
  }
  __syncthreads();
  for (int idx = tid; idx < AGG * 48; idx += 256) {
    int a = idx / 48;
    float v = 0.f;
#pragma unroll
    for (int s = 0; s < 4; s++) v += avpart[((size_t)bh * 4 + s) * 2352 + idx];
    av[(size_t)bh * 2352 + idx] = v * linv[a];
  }
}

// ---------------------------------------------------------------------------
// qattn_dwc_fused: z<512 -> q_attn_v9(z); else dwc_rows(z-512). grid 1408.
// Both branches are LDS-free with similar VGPR budgets -> no worst-branch
// resource penalty; heterogeneous waves co-schedule for latency hiding.
// ---------------------------------------------------------------------------
__global__ __launch_bounds__(256) void qattn_dwc_fused(
    const unsigned short* __restrict__ qkv, const unsigned short* __restrict__ agbf,
    const unsigned short* __restrict__ cb1t, float* __restrict__ opart,
    float* __restrict__ rowsum, float* __restrict__ edge0,
    float* __restrict__ edge1) {
  int z = blockIdx.x;
  int tid = threadIdx.x, lane = tid & 63, wv = tid >> 6;
  int lo = lane & 15, g = lane >> 4;

  if (z < 512) {
    // ======================= q attention (psum, v9) =======================
    int s = z & 3;
    int h = (z >> 2) & 7;
    int b = z >> 5;
    int slot = s * 4 + wv;
    int cstart = (slot == 0) ? 0 : 3 * slot + 1;
    int ccount = (slot == 0) ? 4 : 3;
    int bh = b * 8 + h;

    short8 af0[4], af1[4];
#pragma unroll
    for (int mt = 0; mt < 4; mt++) {
      int a = mt * 16 + lo;
      int ac = a < AGG ? a : AGG - 1;
      const unsigned short* p = agbf + ((size_t)b * AGG + ac) * CC + h * 48;
      af0[mt] = *(const short8*)(p + g * 8);
      if (g < 2) af1[mt] = *(const short8*)(p + 32 + g * 8);
      else { short8 zz = {0, 0, 0, 0, 0, 0, 0, 0}; af1[mt] = zz; }
    }

    float psum[4][4];
#pragma unroll
    for (int mt = 0; mt < 4; mt++)
#pragma unroll
      for (int r = 0; r < 4; r++) psum[mt][r] = 0.f;

    for (int ci = 0; ci < ccount; ci++) {
      int nb = (cstart + ci) * 64;

      short8 qf0[4], qf1[4];
#pragma unroll
      for (int nt = 0; nt < 4; nt++) {
        const unsigned short* qp = qkv + ((size_t)b * NN + nb + nt * 16 + lo) * QKVC + h * 48;
        qf0[nt] = *(const short8*)(qp + g * 8);
        if (g < 2) qf1[nt] = *(const short8*)(qp + 32 + g * 8);
        else { short8 zz = {0, 0, 0, 0, 0, 0, 0, 0}; qf1[nt] = zz; }
      }
      ushort4 cbv[4][4];
#pragma unroll
      for (int mt = 0; mt < 4; mt++)
#pragma unroll
        for (int nt = 0; nt < 4; nt++)
          cbv[mt][nt] = *(const ushort4*)&cb1t[((size_t)h * NN + nb + nt * 16 + lo) * 52 + mt * 16 + g * 4];

      f32x4 acc[4][4];
#pragma unroll
      for (int mt = 0; mt < 4; mt++)
#pragma unroll
        for (int nt = 0; nt < 4; nt++) acc[mt][nt] = (f32x4)0.f;
#pragma unroll
      for (int mt = 0; mt < 4; mt++)
#pragma unroll
        for (int nt = 0; nt < 4; nt++) {
          acc[mt][nt] = __builtin_amdgcn_mfma_f32_16x16x32_bf16(af0[mt], qf0[nt], acc[mt][nt], 0, 0, 0);
          acc[mt][nt] = __builtin_amdgcn_mfma_f32_16x16x32_bf16(af1[mt], qf1[nt], acc[mt][nt], 0, 0, 0);
        }

#pragma unroll
      for (int nt = 0; nt < 4; nt++) {
        float lsum = 0.f;
#pragma unroll
        for (int mt = 0; mt < 4; mt++) {
          unsigned short cb4[4] = {cbv[mt][nt].x, cbv[mt][nt].y, cbv[mt][nt].z, cbv[mt][nt].w};
#pragma unroll
          for (int r = 0; r < 4; r++) {
            int a = mt * 16 + g * 4 + r;
            float e = 0.f;
            if (a < AGG) e = __expf(acc[mt][nt][r] * SCALE_F + bf2f(cb4[r]));
            acc[mt][nt][r] = e;
            lsum += e;
          }
        }
        lsum += __shfl_xor(lsum, 16);
        lsum += __shfl_xor(lsum, 32);
        float inv = 1.f / lsum;
#pragma unroll
        for (int mt = 0; mt < 4; mt++)
#pragma unroll
          for (int r = 0; r < 4; r++)
            psum[mt][r] += acc[mt][nt][r] * inv;
      }
    }

    size_t pbase = (size_t)bh * 16 + slot;
#pragma unroll
    for (int mt = 0; mt < 4; mt++)
#pragma unroll
      for (int r = 0; r < 4; r++) {
        float v = psum[mt][r];
        v += __shfl_xor(v, 1); v += __shfl_xor(v, 2);
        v += __shfl_xor(v, 4); v += __shfl_xor(v, 8);
        int a = mt * 16 + g * 4 + r;
        if (lo == 0 && a < AGG) opart[pbase * 52 + a] = v;
      }

  } else {
    // ======================= dwc rows =======================
    int zz = z - 512;
    int b = zz / HI, r = zz % HI;
    for (int c = tid; c < CC; c += 256) {
      const unsigned short* base = qkv + ((size_t)b * NN + (size_t)r * WI) * QKVC + 768 + c;
      float sum = 0.f, e0v = 0.f, e1v = 0.f;
      for (int w = 0; w < WI; w++) {
        float v = bf2f(base[(size_t)w * QKVC]);
        sum += v;
        if (w == 0) e0v = v;
        if (w == WI - 1) e1v = v;
      }
      rowsum[(size_t)zz * CC + c] = sum;
      edge0[(size_t)zz * CC + c] = e0v;
      edge1[(size_t)zz * CC + c] = e1v;
    }
  }
}

// pass 2a — partial combine over 8-row chunks. grid (16*7) x 384.
__global__ __launch_bounds__(384) void dwc_combine1(const float* __restrict__ rowsum,
                                                    const float* __restrict__ edge0,
                                                    const float* __restrict__ edge1,
                                                    float* __restrict__ dpart,
                                                    float* __restrict__ dedge) {
  int z = blockIdx.x;
  int b = z / 7, rc = z % 7;
  int c = threadIdx.x;
  float T = 0.f, C0 = 0.f, C55 = 0.f;
#pragma unroll
  for (int rr = 0; rr < 8; rr++) {
    int r = rc * 8 + rr;
    size_t idx = ((size_t)(b * HI + r)) * CC + c;
    float rs = rowsum[idx], a0 = edge0[idx], a1 = edge1[idx];
    T += rs; C0 += a0; C55 += a1;
    if (r == 0) {
      dedge[((size_t)b * 6 + 0) * CC + c] = rs;
      dedge[((size_t)b * 6 + 1) * CC + c] = a0;
      dedge[((size_t)b * 6 + 2) * CC + c] = a1;
    }
    if (r == HI - 1) {
      dedge[((size_t)b * 6 + 3) * CC + c] = rs;
      dedge[((size_t)b * 6 + 4) * CC + c] = a0;
      dedge[((size_t)b * 6 + 5) * CC + c] = a1;
    }
  }
  size_t pb = ((size_t)(b * 7 + rc) * 3) * CC + c;
  dpart[pb] = T;
  dpart[pb + CC] = C0;
  dpart[pb + 2 * CC] = C55;
}

// ---------------------------------------------------------------------------
// head_pre: pre[b][k] = (dwc(k) + attn(k))/NN + dwc_b, where
// attn(k) = sum_a psum[h(k)][a] * av[b,h(k)][a][d(k)]. grid 16 x 384.
// ---------------------------------------------------------------------------
__global__ __launch_bounds__(384) void head_pre(const float* __restrict__ dpart,
                                                const float* __restrict__ dedge,
                                                const float* __restrict__ opart,
                                                const float* __restrict__ av,
                                                const float* __restrict__ w,
                                                const float* __restrict__ dwc_b,
                                                float* __restrict__ pre) {
  int b = blockIdx.x;
  int k = threadIdx.x;
  __shared__ float psums[HDS][AGG];
  for (int idx = k; idx < HDS * AGG; idx += 384) {
    int hh = idx / AGG, a = idx % AGG;
    float v = 0.f;
#pragma unroll
    for (int s = 0; s < 16; s++)
      v += opart[(((size_t)(b * 8 + hh) * 16) + s) * 52 + a];
    psums[hh][a] = v;
  }
  __syncthreads();

  float T = 0.f, C0 = 0.f, C55 = 0.f;
#pragma unroll
  for (int rc = 0; rc < 7; rc++) {
    size_t pb = ((size_t)(b * 7 + rc) * 3) * CC + k;
    T += dpart[pb];
    C0 += dpart[pb + CC];
    C55 += dpart[pb + 2 * CC];
  }
  float R0 = dedge[((size_t)b * 6 + 0) * CC + k];
  float v00 = dedge[((size_t)b * 6 + 1) * CC + k];
  float v0W = dedge[((size_t)b * 6 + 2) * CC + k];
  float R55 = dedge[((size_t)b * 6 + 3) * CC + k];
  float vH0 = dedge[((size_t)b * 6 + 4) * CC + k];
  float vHW = dedge[((size_t)b * 6 + 5) * CC + k];
  float dwcsum = 0.f;
#pragma unroll
  for (int i = 0; i < 3; i++) {
    int di = i - 1;
#pragma unroll
    for (int j = 0; j < 3; j++) {
      int dj = j - 1;
      float S = T;
      if (di == 1) S -= R0; else if (di == -1) S -= R55;
      if (dj == 1) S -= C0; else if (dj == -1) S -= C55;
      if (di != 0 && dj != 0)
        S += (di == 1) ? ((dj == 1) ? v00 : v0W) : ((dj == 1) ? vH0 : vHW);
      dwcsum += w[k * 9 + i * 3 + j] * S;
    }
  }

  int hh = k / 48, dd = k % 48;
  const float* avb = av + ((size_t)(b * 8 + hh)) * 2352 + dd;
  float attn = 0.f;
#pragma unroll 7
  for (int a = 0; a < AGG; a++) attn += psums[hh][a] * avb[(size_t)a * 48];
  pre[(size_t)b * CC + k] = (dwcsum + attn) * (1.f / (float)NN) + dwc_b[k];
}

// head_proj_part: K=384 split x6. waves = 16b x 6oc x 6kc = 576; grid 144.
__global__ __launch_bounds__(256) void head_proj_part(
    const float* __restrict__ pre, const float* __restrict__ Wproj,
    float* __restrict__ pjpart) {
  int w = blockIdx.x * 4 + (threadIdx.x >> 6);
  int lane = threadIdx.x & 63;
  int b = w / 36, rem = w % 36;
  int oc = rem / 6, kc = rem % 6;
  int o = oc * 64 + lane;
  const float* pb = pre + (size_t)b * CC + kc * 64;
  const float* wp2 = Wproj + (size_t)(kc * 64) * CC + o;
  float s = 0.f;
#pragma unroll 16
  for (int k = 0; k < 64; k++) s += pb[k] * wp2[(size_t)k * CC];
  pjpart[((size_t)(b * 6 + kc)) * CC + o] = s;
}

__global__ __launch_bounds__(384) void head_ln6(const float* __restrict__ pjpart,
                                                const float* __restrict__ bproj,
                                                const float* __restrict__ ln_g,
                                                const float* __restrict__ ln_b,
                                                float* __restrict__ h0) {
  int b = blockIdx.x;
  int tid = threadIdx.x;
  __shared__ float red[8];
  float v = bproj[tid];
#pragma unroll
  for (int kc = 0; kc < 6; kc++) v += pjpart[((size_t)(b * 6 + kc)) * CC + tid];
  float m;
  {
    float s = v;
#pragma unroll
    for (int o = 32; o > 0; o >>= 1) s += __shfl_down(s, o);
    if ((tid & 63) == 0) red[tid >> 6] = s;
    __syncthreads();
    if (tid == 0) {
      float t = 0.f;
      for (int i = 0; i < 6; i++) t += red[i];
      red[6] = t * (1.f / (float)CC);
    }
    __syncthreads();
    m = red[6];
  }
  float dv = v - m;
  __syncthreads();
  float var;
  {
    float s = dv * dv;
#pragma unroll
    for (int o = 32; o > 0; o >>= 1) s += __shfl_down(s, o);
    if ((tid & 63) == 0) red[tid >> 6] = s;
    __syncthreads();
    if (tid == 0) {
      float t = 0.f;
      for (int i = 0; i < 6; i++) t += red[i];
      red[7] = t * (1.f / (float)CC);
    }
    __syncthreads();
    var = red[7];
  }
  h0[(size_t)b * CC + tid] = dv * rsqrtf(var + 1e-5f) * ln_g[tid] + ln_b[tid];
}

__global__ __launch_bounds__(256) void head_mlp1_part(
    const float* __restrict__ h0, const float* __restrict__ W1,
    float* __restrict__ h1part) {
  int w = blockIdx.x * 4 + (threadIdx.x >> 6);
  int lane = threadIdx.x & 63;
  int b = w / 72, rem = w % 72;
  int oc = rem / 6, kc = rem % 6;
  int o = oc * 64 + lane;
  const float* hb = h0 + (size_t)b * CC + kc * 64;
  const float* wp2 = W1 + (size_t)(kc * 64) * (2 * CC) + o;
  float s = 0.f;
#pragma unroll 16
  for (int k = 0; k < 64; k++) s += hb[k] * wp2[(size_t)k * (2 * CC)];
  h1part[((size_t)(b * 6 + kc)) * (2 * CC) + o] = s;
}

__global__ __launch_bounds__(256) void head_mlp1_red(const float* __restrict__ h1part,
                                                     const float* __restrict__ b1,
                                                     float* __restrict__ h1) {
  int b = blockIdx.x;
  for (int o = threadIdx.x; o < 2 * CC; o += 256) {
    float s = b1[o];
#pragma unroll
    for (int kc = 0; kc < 6; kc++) s += h1part[((size_t)(b * 6 + kc)) * (2 * CC) + o];
    h1[(size_t)b * (2 * CC) + o] = 0.5f * s * (1.f + erff(s * 0.70710678118654752f));
  }
}

__global__ __launch_bounds__(256) void head_mlp2_part(
    const float* __restrict__ h1, const float* __restrict__ W2,
    float* __restrict__ o2part) {
  int w = blockIdx.x * 4 + (threadIdx.x >> 6);
  int lane = threadIdx.x & 63;
  int b = w / 192, rem = w % 192;
  int oc = rem / 12, kc = rem % 12;
  int o = oc * 64 + lane;
  int ocl = o < OUTD ? o : OUTD - 1;
  const float* hb = h1 + (size_t)b * (2 * CC) + kc * 64;
  const float* wp2 = W2 + (size_t)(kc * 64) * OUTD + ocl;
  float s = 0.f;
#pragma unroll 16
  for (int k = 0; k < 64; k++) s += hb[k] * wp2[(size_t)k * OUTD];
  o2part[((size_t)(b * 12 + kc)) * 1024 + o] = s;
}

__global__ __launch_bounds__(256) void head_out(const float* __restrict__ o2part,
                                                const float* __restrict__ b2,
                                                float* __restrict__ out) {
  int b = blockIdx.x;
  for (int o = threadIdx.x; o < OUTD; o += 256) {
    float s = b2[o];
#pragma unroll
    for (int kc = 0; kc < 12; kc++) s += o2part[((size_t)(b * 12 + kc)) * 1024 + o];
    out[(size_t)b * OUTD + o] = s;
  }
}

// ---------------------------------------------------------------------------
extern "C" void kernel_launch(void* const* d_in, const int* in_sizes, int n_in,
                              void* d_out, int out_size, void* d_ws,
                              size_t ws_size, hipStream_t stream) {
  const float* x = (const float*)d_in[0];
  const float* Wq = (const float*)d_in[1];
  const float* Wkv = (const float*)d_in[2];
  const float* an_bias = (const float*)d_in[3];
  const float* na_bias = (const float*)d_in[4];
  const float* ah_bias = (const float*)d_in[5];
  const float* aw_bias = (const float*)d_in[6];
  const float* ha_bias = (const float*)d_in[7];
  const float* wa_bias = (const float*)d_in[8];
  const float* dwc_w = (const float*)d_in[9];
  const float* dwc_b = (const float*)d_in[10];
  const float* Wproj = (const float*)d_in[11];
  const float* bproj = (const float*)d_in[12];
  const float* ln_g = (const float*)d_in[13];
  const float* ln_b = (const float*)d_in[14];
  const float* W1 = (const float*)d_in[15];
  const float* b1 = (const float*)d_in[16];
  const float* W2 = (const float*)d_in[17];
  const float* b2 = (const float*)d_in[18];
  float* out = (float*)d_out;

  const size_t M = (size_t)BB * NN;  // 50176
  char* wsp = (char*)d_ws;
  unsigned short* xp = (unsigned short*)wsp;    // reused as vtp after gemm
  unsigned short* vtp = xp;
  wsp += M * CC * 2;
  unsigned short* wpb = (unsigned short*)wsp;   wsp += (size_t)QKVC * CC * 2;
  unsigned short* qkv = (unsigned short*)wsp;   wsp += M * QKVC * 2;
  unsigned short* agbf = (unsigned short*)wsp;  wsp += (size_t)784 * CC * 2;
  unsigned short* cb1t = (unsigned short*)wsp;  wsp += (size_t)HDS * NN * 52 * 2;
  unsigned short* cb2t = (unsigned short*)wsp;  wsp += (size_t)HDS * NN * 52 * 2;
  float* lpart = (float*)wsp;                   wsp += (size_t)128 * 4 * AGG * 4;
  float* avpart = (float*)wsp;                  wsp += (size_t)128 * 4 * 2352 * 4;
  float* av = (float*)wsp;                      wsp += (size_t)128 * 2352 * 4;
  float* opart = (float*)wsp;                   wsp += (size_t)128 * 16 * 52 * 4;
  float* rowsum = (float*)wsp;                  wsp += (size_t)BB * HI * CC * 4;
  float* edge0 = (float*)wsp;                   wsp += (size_t)BB * HI * CC * 4;
  float* edge1 = (float*)wsp;                   wsp += (size_t)BB * HI * CC * 4;
  float* dpart = (float*)wsp;                   wsp += (size_t)BB * 7 * 3 * CC * 4;
  float* dedge = (float*)wsp;                   wsp += (size_t)BB * 6 * CC * 4;
  float* pre = (float*)wsp;                     wsp += (size_t)BB * CC * 4;
  float* pjpart = (float*)wsp;                  wsp += (size_t)BB * 6 * CC * 4;
  float* h0b = (float*)wsp;                     wsp += (size_t)BB * CC * 4;
  float* h1part = (float*)wsp;                  wsp += (size_t)BB * 6 * 2 * CC * 4;
  float* h1b = (float*)wsp;                     wsp += (size_t)BB * 2 * CC * 4;
  float* o2part = (float*)wsp;                  wsp += (size_t)BB * 12 * 1024 * 4;

  dim3 blk256(256);
  hipLaunchKernelGGL(pack_x, dim3(784), blk256, 0, stream, x, xp);
  hipLaunchKernelGGL(pack_w, dim3(18), blk256, 0, stream, Wq, Wkv, wpb);
  hipLaunchKernelGGL(make_cbias2, dim3(HDS * 49), blk256, 0, stream, na_bias,
                     ha_bias, wa_bias, an_bias, ah_bias, aw_bias, cb1t, cb2t);
  hipLaunchKernelGGL(gemm_v4, dim3(1764), blk256, 0, stream, xp, wpb, qkv);
  // xp dead from here; vtp aliases it
  hipLaunchKernelGGL(pack_vt, dim3(BB * 49), blk256, 0, stream, qkv, vtp);
  hipLaunchKernelGGL(pool_agent, dim3(BB * AGG), dim3(384), 0, stream, qkv, agbf);
  hipLaunchKernelGGL(agent_attn_v5, dim3(BB * HDS * 4), blk256, 0, stream,
                     qkv, agbf, cb2t, vtp, lpart, avpart);
  hipLaunchKernelGGL(qattn_dwc_fused, dim3(1408), blk256, 0, stream, qkv, agbf,
                     cb1t, opart, rowsum, edge0, edge1);
  hipLaunchKernelGGL(av_normalize4, dim3(BB * HDS), blk256, 0, stream, lpart,
                     avpart, av);
  hipLaunchKernelGGL(dwc_combine1, dim3(BB * 7), dim3(384), 0, stream, rowsum,
                     edge0, edge1, dpart, dedge);
  hipLaunchKernelGGL(head_pre, dim3(BB), dim3(384), 0, stream, dpart, dedge,
                     opart, av, dwc_w, dwc_b, pre);
  hipLaunchKernelGGL(head_proj_part, dim3(144), blk256, 0, stream, pre, Wproj, pjpart);
  hipLaunchKernelGGL(head_ln6, dim3(BB), dim3(384), 0, stream, pjpart, bproj,
                     ln_g, ln_b, h0b);
  hipLaunchKernelGGL(head_mlp1_part, dim3(288), blk256, 0, stream, h0b, W1, h1part);
  hipLaunchKernelGGL(head_mlp1_red, dim3(BB), blk256, 0, stream, h1part, b1, h1b);
  hipLaunchKernelGGL(head_mlp2_part, dim3(768), blk256, 0, stream, h1b, W2, o2part);
  hipLaunchKernelGGL(head_out, dim3(BB), blk256, 0, stream, o2part, b2, out);
}